// Round 1
// 137.921 us; speedup vs baseline: 1.0346x; 1.0346x over previous
//
#include <hip/hip_runtime.h>
#include <hip/hip_fp16.h>

// GraphConv: out = segment_sum(w * X[src] -> dst) @ W + b
// = gather of w * (X@W)[src] per dst (matmul distributes over segment-sum).
// Round 10: fuse bin_kernel into the X@W launch (role-split blocks, 3:2
// interleave) so the edge-stream binning overlaps the MFMA/stream-bound XW
// phase. gcnt/oc zeroing moves to a ~1us single-block kernel launched first
// (stream-ordered -> no cross-block ordering assumptions). LDS is a union
// (bin 68KB | xw 18.4KB) -> 2 blocks/CU x 8 waves = 16 waves/CU for xw,
// identical to the baseline's VGPR-capped 16 waves/CU.
// bucket_gather_kernel is unchanged (verified absmax 0.0625).
//
// V=100000, E=1250000, C=64, fp32 in/out.

constexpr int V = 100000;
constexpr int E = 1250000;
constexpr int C = 64;

constexpr int NBKT = 1024;        // dst buckets
constexpr int VB   = 98;          // vertices per bucket (1024*98 >= V)
constexpr int BCAP = 1536;        // records per bucket (mean 1221, +9 sigma)
constexpr int FL   = 8;           // LDS staging slots per bucket in bin role
constexpr int OVF_CAP = 16384;

// ---------------- workspace layout (bytes) ----------------
constexpr size_t Y_OFF    = 0;           // V*C*2 = 12,800,000 (fp16)
constexpr size_t BIN_OFF  = 12800000;    // NBKT*BCAP*8 = 12,582,912
constexpr size_t GCNT_OFF = 25382912;    // NBKT*4 = 4,096
constexpr size_t OC_OFF   = 25387008;    // 16
constexpr size_t OVF_OFF  = 25387024;    // OVF_CAP*16 = 262,144
constexpr size_t WS_NEW   = 25649168;

using bf16x8 = __attribute__((ext_vector_type(8))) short;
using f32x4  = __attribute__((ext_vector_type(4))) float;

__device__ __forceinline__ short f2bf(float x) {          // RNE float->bf16 bits
    unsigned u = __float_as_uint(x);
    unsigned r = u + 0x7fffu + ((u >> 16) & 1u);
    return (short)(r >> 16);
}
__device__ __forceinline__ float bf2f(short h) {
    return __uint_as_float(((unsigned)(unsigned short)h) << 16);
}

// ---------------------------------------------------------------------------
// Tiny zero kernel: gcnt (1024 ints) + oc. ~1us, stream-ordered before the
// fused kernel so the bin role's spill/flush atomics see zeroed counters.
// ---------------------------------------------------------------------------
__global__ __launch_bounds__(256) void zero_kernel(int* __restrict__ gcnt,
                                                   int* __restrict__ oc) {
    int i = threadIdx.x;
    #pragma unroll
    for (int j = 0; j < NBKT / 256; ++j) gcnt[i + j * 256] = 0;
    if (i == 0) *oc = 0;
}

// ---------------------------------------------------------------------------
// Fused XW + bin kernel. 512-thread blocks, grid = 261 groups x 5 blocks:
// slots 0-2 -> xw role (782 blocks x 8 waves = 6256 chunks >= 6250),
// slots 3-4 -> bin role (512 blocks). Interleave keeps both roles resident
// on every CU throughout, so the bin phase hides behind xw.
//
// xw role: per wave one 16-row chunk; 3-term bf16 split MFMA (verified
// rounds 4-9: absmax 0.0625). Y written fp16.
// bin role: records staged per-bucket in LDS, flushed at the end in
// contiguous bursts (one global atomic per bucket per block).
// Record = (local_dst<<17|src, w). Per-(block,bucket) mean 2.38 at 512
// bin blocks -> staging spill ~0.1% (direct global path, gcnt zeroed by
// zero_kernel).
// ---------------------------------------------------------------------------
constexpr int FUSE_T    = 512;
constexpr int XWB       = 782;           // xw role blocks
constexpr int BINB      = 512;           // bin role blocks
constexpr int FUSE_GRID = 261 * 5;       // 1305 (last group partially idle)

__global__ __launch_bounds__(FUSE_T) void xwbin_kernel(
        const float* __restrict__ X,
        const float* __restrict__ W,
        __half*      __restrict__ Y,
        const int*   __restrict__ esrc,
        const int*   __restrict__ edst,
        const float* __restrict__ ew,
        int*  __restrict__ gcnt,
        int2* __restrict__ binned,
        int*  __restrict__ oc,
        int4* __restrict__ ovf) {
    __shared__ union {
        struct { short Whi[64 * 72]; short Wlo[64 * 72]; } xw;   // 18.4 KB
        struct { int2 stage[NBKT][FL]; int lcnt[NBKT]; } bin;    // 68 KB
    } u;

    const int grp  = blockIdx.x / 5;
    const int slot = blockIdx.x % 5;

    if (slot < 3) {
        // ------------------------------ XW role ------------------------------
        const int xb = grp * 3 + slot;
        if (xb >= XWB) return;

        for (int idx = threadIdx.x; idx < 4096; idx += FUSE_T) {
            int k = idx >> 6, c = idx & 63;
            float w  = W[idx];
            short hi = f2bf(w);
            short lo = f2bf(w - bf2f(hi));
            u.xw.Whi[c * 72 + k] = hi;
            u.xw.Wlo[c * 72 + k] = lo;
        }
        __syncthreads();

        const int wave = threadIdx.x >> 6;       // 0..7
        const int lane = threadIdx.x & 63;
        const int m = lane & 15;
        const int q = lane >> 4;

        bf16x8 bhi[4][2], blo[4][2];
        #pragma unroll
        for (int t = 0; t < 4; ++t)
            #pragma unroll
            for (int h = 0; h < 2; ++h) {
                int o = (t * 16 + m) * 72 + h * 32 + q * 8;
                bhi[t][h] = *(const bf16x8*)&u.xw.Whi[o];
                blo[t][h] = *(const bf16x8*)&u.xw.Wlo[o];
            }

        const int chunk = xb * 8 + wave;
        if (chunk >= V / 16) return;
        {
            const float* xp = X + (chunk * 16 + m) * 64 + q * 8;
            bf16x8 ahi[2], alo[2];
            #pragma unroll
            for (int h = 0; h < 2; ++h) {
                float4 f0 = *(const float4*)(xp + h * 32);
                float4 f1 = *(const float4*)(xp + h * 32 + 4);
                float f[8] = {f0.x, f0.y, f0.z, f0.w, f1.x, f1.y, f1.z, f1.w};
                #pragma unroll
                for (int j = 0; j < 8; ++j) {
                    short hi = f2bf(f[j]);
                    ahi[h][j] = hi;
                    alo[h][j] = f2bf(f[j] - bf2f(hi));
                }
            }
            #pragma unroll
            for (int t = 0; t < 4; ++t) {
                f32x4 acc = {0.f, 0.f, 0.f, 0.f};
                #pragma unroll
                for (int h = 0; h < 2; ++h) {
                    acc = __builtin_amdgcn_mfma_f32_16x16x32_bf16(ahi[h], bhi[t][h], acc, 0, 0, 0);
                    acc = __builtin_amdgcn_mfma_f32_16x16x32_bf16(alo[h], bhi[t][h], acc, 0, 0, 0);
                    acc = __builtin_amdgcn_mfma_f32_16x16x32_bf16(ahi[h], blo[t][h], acc, 0, 0, 0);
                }
                #pragma unroll
                for (int i = 0; i < 4; ++i) {
                    int row = chunk * 16 + q * 4 + i;
                    Y[row * 64 + t * 16 + m] = __float2half(acc[i]);
                }
            }
        }
    } else {
        // ------------------------------ bin role -----------------------------
        const int bb = grp * 2 + (slot - 3);
        if (bb >= BINB) return;

        for (int i = threadIdx.x; i < NBKT; i += FUSE_T) u.bin.lcnt[i] = 0;
        __syncthreads();

        const int iters = (E + BINB * FUSE_T - 1) / (BINB * FUSE_T);   // 5
        for (int it = 0; it < iters; ++it) {
            int e = (it * BINB + bb) * FUSE_T + threadIdx.x;
            if (e < E) {
                int d = edst[e];
                int s = esrc[e];
                float w = ew[e];
                int bkt = d / VB;
                int ld  = d - bkt * VB;
                int2 rec = make_int2((ld << 17) | s, __float_as_int(w));
                int pos = atomicAdd(&u.bin.lcnt[bkt], 1);
                if (pos < FL) {
                    u.bin.stage[bkt][pos] = rec;
                } else {                              // staging spill (~0.1%)
                    int g = atomicAdd(&gcnt[bkt], 1);
                    if (g < BCAP) binned[bkt * BCAP + g] = rec;
                    else { int p = atomicAdd(oc, 1);
                           if (p < OVF_CAP) ovf[p] = make_int4(s, d, __float_as_int(w), 0); }
                }
            }
        }
        __syncthreads();
        // final flush: one thread per bucket — contiguous burst each
        for (int b = threadIdx.x; b < NBKT; b += FUSE_T) {
            int n = u.bin.lcnt[b]; n = n < FL ? n : FL;
            if (n > 0) {
                int g = atomicAdd(&gcnt[b], n);
                for (int i = 0; i < n; ++i) {
                    int gi = g + i;
                    int2 r = u.bin.stage[b][i];
                    if (gi < BCAP) binned[b * BCAP + gi] = r;
                    else { int s = r.x & 0x1FFFF; int ld = r.x >> 17;
                           int p = atomicAdd(oc, 1);
                           if (p < OVF_CAP) ovf[p] = make_int4(s, b * VB + ld, r.y, 0); }
                }
            }
        }
    }
}

// ---------------------------------------------------------------------------
// Bucket gather: UNCHANGED from r9 (verified). One 512-thread block per
// bucket (27 KB LDS -> 4 blocks/CU, 32 waves/CU). Counting-sort the bucket's
// records in LDS, then per-vertex register gather (wave per vertex,
// lane = channel, fp16 Y, fused bias) with 8 outstanding Y loads.
// ---------------------------------------------------------------------------
__global__ __launch_bounds__(512) void bucket_gather_kernel(const int*  __restrict__ gcnt,
                                                            const int2* __restrict__ binned,
                                                            const int*  __restrict__ oc,
                                                            const int4* __restrict__ ovf,
                                                            const __half* __restrict__ Y,
                                                            const float* __restrict__ bias,
                                                            float* __restrict__ out) {
    __shared__ int2 raw[BCAP];           // 12 KB
    __shared__ int2 sorted[BCAP];        // 12 KB
    __shared__ int  cnt[VB];
    __shared__ int  pre[VB];
    __shared__ int  cur[VB];
    __shared__ int  buf[128];

    const int tid = threadIdx.x;
    const int b   = blockIdx.x;
    int n = gcnt[b]; n = n < BCAP ? n : BCAP;

    for (int i = tid; i < VB; i += 512) cnt[i] = 0;
    __syncthreads();

    const int2* src = binned + b * BCAP;
    for (int i = tid; i < n; i += 512) {
        int2 r = src[i];
        raw[i] = r;
        atomicAdd(&cnt[r.x >> 17], 1);
    }
    __syncthreads();

    // exclusive scan of cnt[0..VB) over first 128 threads (VB <= 128)
    int x = 0;
    if (tid < 128) { x = (tid < VB) ? cnt[tid] : 0; buf[tid] = x; }
    __syncthreads();
    #pragma unroll
    for (int ofs = 1; ofs < 128; ofs <<= 1) {
        int t = 0;
        if (tid < 128 && tid >= ofs) t = buf[tid - ofs];
        __syncthreads();
        if (tid < 128) buf[tid] += t;
        __syncthreads();
    }
    if (tid < VB) { int ex = buf[tid] - x; pre[tid] = ex; cur[tid] = ex; }
    __syncthreads();

    for (int i = tid; i < n; i += 512) {
        int2 r = raw[i];
        int ld = r.x >> 17;
        int p = atomicAdd(&cur[ld], 1);
        sorted[p] = r;
    }
    __syncthreads();

    const int lane = tid & 63;
    const int wv   = tid >> 6;           // 0..7
    float bias_l = bias[lane];
    int ovn = *oc; ovn = ovn < OVF_CAP ? ovn : OVF_CAP;   // expected 0

    for (int ld = wv; ld < VB; ld += 8) {
        int v = b * VB + ld;
        if (v >= V) break;
        int beg = pre[ld];
        int end = beg + cnt[ld];
        float acc = 0.f;
        int i = beg;
        for (; i + 8 <= end; i += 8) {           // 8 outstanding Y-row loads
            int2 r0 = sorted[i],     r1 = sorted[i + 1];
            int2 r2 = sorted[i + 2], r3 = sorted[i + 3];
            int2 r4 = sorted[i + 4], r5 = sorted[i + 5];
            int2 r6 = sorted[i + 6], r7 = sorted[i + 7];
            float y0 = __half2float(Y[(r0.x & 0x1FFFF) * C + lane]);
            float y1 = __half2float(Y[(r1.x & 0x1FFFF) * C + lane]);
            float y2 = __half2float(Y[(r2.x & 0x1FFFF) * C + lane]);
            float y3 = __half2float(Y[(r3.x & 0x1FFFF) * C + lane]);
            float y4 = __half2float(Y[(r4.x & 0x1FFFF) * C + lane]);
            float y5 = __half2float(Y[(r5.x & 0x1FFFF) * C + lane]);
            float y6 = __half2float(Y[(r6.x & 0x1FFFF) * C + lane]);
            float y7 = __half2float(Y[(r7.x & 0x1FFFF) * C + lane]);
            acc += __int_as_float(r0.y) * y0;
            acc += __int_as_float(r1.y) * y1;
            acc += __int_as_float(r2.y) * y2;
            acc += __int_as_float(r3.y) * y3;
            acc += __int_as_float(r4.y) * y4;
            acc += __int_as_float(r5.y) * y5;
            acc += __int_as_float(r6.y) * y6;
            acc += __int_as_float(r7.y) * y7;
        }
        for (; i + 4 <= end; i += 4) {
            int2 r0 = sorted[i], r1 = sorted[i + 1], r2 = sorted[i + 2], r3 = sorted[i + 3];
            float y0 = __half2float(Y[(r0.x & 0x1FFFF) * C + lane]);
            float y1 = __half2float(Y[(r1.x & 0x1FFFF) * C + lane]);
            float y2 = __half2float(Y[(r2.x & 0x1FFFF) * C + lane]);
            float y3 = __half2float(Y[(r3.x & 0x1FFFF) * C + lane]);
            acc += __int_as_float(r0.y) * y0;
            acc += __int_as_float(r1.y) * y1;
            acc += __int_as_float(r2.y) * y2;
            acc += __int_as_float(r3.y) * y3;
        }
        for (; i < end; ++i) {
            int2 rr = sorted[i];
            acc += __int_as_float(rr.y) * __half2float(Y[(rr.x & 0x1FFFF) * C + lane]);
        }
        // overflow backstop (ovn expected 0)
        for (int k = 0; k < ovn; ++k) {
            int4 rr = ovf[k];
            if (rr.y == v)
                acc += __int_as_float(rr.z) * __half2float(Y[rr.x * C + lane]);
        }
        out[v * C + lane] = acc + bias_l;
    }
}

// ===========================================================================
// Fallback (ws too small): fp32 Y + bias init + fp32 atomic scatter
// ===========================================================================
__global__ __launch_bounds__(256) void xw_kernel(const float* __restrict__ X,
                                                 const float* __restrict__ W,
                                                 float* __restrict__ Y) {
    __shared__ float Ws[64][64];
    const float4* W4 = (const float4*)W;
    float4* Ws4 = (float4*)&Ws[0][0];
    #pragma unroll
    for (int i = 0; i < 4; ++i)
        Ws4[threadIdx.x + 256 * i] = W4[threadIdx.x + 256 * i];
    __syncthreads();
    const int wave = threadIdx.x >> 6;
    const int lane = threadIdx.x & 63;
    for (int row = blockIdx.x * 4 + wave; row < V; row += gridDim.x * 4) {
        float xv = X[row * C + lane];
        float acc = 0.f;
        #pragma unroll
        for (int k = 0; k < C; ++k)
            acc += __shfl(xv, k, 64) * Ws[k][lane];
        Y[row * C + lane] = acc;
    }
}

__global__ __launch_bounds__(256) void init_out_kernel(const float* __restrict__ b,
                                                       float4* __restrict__ out4) {
    int tid = blockIdx.x * 256 + threadIdx.x;
    const int n4 = V * (C / 4);
    if (tid < n4) {
        const float4* b4 = (const float4*)b;
        out4[tid] = b4[tid & 15];
    }
}

__global__ __launch_bounds__(256) void scatter_kernel(const int*   __restrict__ esrc,
                                                      const int*   __restrict__ edst,
                                                      const float* __restrict__ ew,
                                                      const float* __restrict__ Y,
                                                      float*       __restrict__ out) {
    unsigned tid = blockIdx.x * 256u + threadIdx.x;
    unsigned e = tid >> 4;
    if (e >= (unsigned)E) return;
    int g = (tid & 15) * 4;
    int   s  = esrc[e];
    int   d  = edst[e];
    float we = ew[e];
    float4 y = *(const float4*)(Y + s * C + g);
    float* o = out + (size_t)d * C + g;
    atomicAdd(o + 0, we * y.x);
    atomicAdd(o + 1, we * y.y);
    atomicAdd(o + 2, we * y.z);
    atomicAdd(o + 3, we * y.w);
}

extern "C" void kernel_launch(void* const* d_in, const int* in_sizes, int n_in,
                              void* d_out, int out_size, void* d_ws, size_t ws_size,
                              hipStream_t stream) {
    const float* X    = (const float*)d_in[0];
    const int*   esrc = (const int*)  d_in[1];
    const int*   edst = (const int*)  d_in[2];
    const float* ew   = (const float*)d_in[3];
    const float* W    = (const float*)d_in[4];
    const float* b    = (const float*)d_in[5];
    float* out = (float*)d_out;

    char* ws = (char*)d_ws;

    if (ws_size >= WS_NEW) {
        __half* Y     = (__half*)(ws + Y_OFF);
        int2*  binned = (int2*)(ws + BIN_OFF);
        int*   gcnt   = (int*) (ws + GCNT_OFF);
        int*   oc     = (int*) (ws + OC_OFF);
        int4*  ovf    = (int4*)(ws + OVF_OFF);

        zero_kernel<<<1, 256, 0, stream>>>(gcnt, oc);
        xwbin_kernel<<<FUSE_GRID, FUSE_T, 0, stream>>>(X, W, Y, esrc, edst, ew,
                                                       gcnt, binned, oc, ovf);
        bucket_gather_kernel<<<NBKT, 512, 0, stream>>>(gcnt, binned, oc, ovf, Y, b, out);
    } else {
        float* Y = (float*)(ws + Y_OFF);
        xw_kernel<<<1024, 256, 0, stream>>>(X, W, Y);
        init_out_kernel<<<(V * (C / 4) + 255) / 256, 256, 0, stream>>>(b, (float4*)out);
        scatter_kernel<<<(E * 16 + 255) / 256, 256, 0, stream>>>(esrc, edst, ew, Y, out);
    }
}